// Round 3
// baseline (80.354 us; speedup 1.0000x reference)
//
#include <hip/hip_runtime.h>

// x[2][4][128][128][128] f32, y[2][1][128][128][128] int32
constexpr float EPSV = 1e-6f;
constexpr int ZSEG = 4;                 // z-slices per wave
constexpr int NSEG = 128 / ZSEG;        // 32 segments
constexpr int NWAVE = 2 * NSEG * 128;   // 8192 waves
constexpr int NBLK = NWAVE / 4;         // 2048 blocks of 4 waves

// Ring state per z-slice: y-direction products of (1-x) per class for the
// lane's two x positions, plus class-presence OR over the 3 y-rows.
struct Ring {
    float ypx[4], ypy[4];
    int yor;  // bits0-3 -> x0 presence, bits8-11 -> x0+1 presence
};

__device__ __forceinline__ Ring load_ring(const float* __restrict__ xb,
                                          const int* __restrict__ yb,
                                          int s, int rbase0, bool ym1, bool yp1) {
    Ring r;
    const int rb = (s << 14) | rbase0;

    int2 vm = ym1 ? *(const int2*)(yb + rb - 128) : make_int2(0, 0);
    int2 vc = *(const int2*)(yb + rb);
    int2 vp = yp1 ? *(const int2*)(yb + rb + 128) : make_int2(0, 0);
    const int mm = ym1 ? ((1 << vm.x) | (1 << vm.y) << 8) : 0;
    const int mc = (1 << vc.x) | (1 << vc.y) << 8;
    const int mp = yp1 ? ((1 << vp.x) | (1 << vp.y) << 8) : 0;
    r.yor = mm | mc | mp;

#pragma unroll
    for (int c = 0; c < 4; ++c) {
        const float* p = xb + (c << 21) + rb;
        float2 am = ym1 ? *(const float2*)(p - 128) : make_float2(0.f, 0.f);
        float2 ac = *(const float2*)(p);
        float2 ap = yp1 ? *(const float2*)(p + 128) : make_float2(0.f, 0.f);
        r.ypx[c] = (1.f - am.x) * (1.f - ac.x) * (1.f - ap.x);
        r.ypy[c] = (1.f - am.y) * (1.f - ac.y) * (1.f - ap.y);
    }
    return r;
}

__device__ __forceinline__ Ring ones_ring() {
    Ring r;
#pragma unroll
    for (int c = 0; c < 4; ++c) { r.ypx[c] = 1.f; r.ypy[c] = 1.f; }
    r.yor = 0;
    return r;
}

__global__ __launch_bounds__(256, 4) void lah_stencil(const float* __restrict__ x,
                                                      const int* __restrict__ y32,
                                                      float* __restrict__ acc) {
    const int wid = (blockIdx.x << 2) | (threadIdx.x >> 6);
    const int lane = threadIdx.x & 63;
    const int b = wid >> 12;            // 4096 waves per batch
    const int rem = wid & 4095;
    const int zs = rem >> 7;            // 0..31
    const int yy = rem & 127;
    const int x0 = lane << 1;
    const int z0 = zs * ZSEG;
    const bool ym1 = yy > 0, yp1v = yy < 127;
    const int rbase0 = (yy << 7) | x0;

    const float* __restrict__ xb = x + ((long)b << 23);
    const int* __restrict__ yb = y32 + ((long)b << 21);

    float fp[4] = {0.f, 0.f, 0.f, 0.f};
    float fnv[4] = {0.f, 0.f, 0.f, 0.f};
    float sx[4] = {0.f, 0.f, 0.f, 0.f};
    float sy[4] = {0.f, 0.f, 0.f, 0.f};

    Ring r0 = (z0 > 0) ? load_ring(xb, yb, z0 - 1, rbase0, ym1, yp1v) : ones_ring();
    Ring r1 = load_ring(xb, yb, z0, rbase0, ym1, yp1v);

#pragma unroll
    for (int dz = 0; dz < ZSEG; ++dz) {
        const int z = z0 + dz;
        Ring r2 = (z + 1 < 128) ? load_ring(xb, yb, z + 1, rbase0, ym1, yp1v)
                                : ones_ring();

        // center-row re-loads (fetched one z-step ago -> L1-hot)
        const int rbc = (z << 14) | rbase0;
        const int2 vcc = *(const int2*)(yb + rbc);
        const int cc0 = vcc.x, cc1 = vcc.y;

        // presence across z, then across x via shuffles
        const int zor = r0.yor | r1.yor | r2.yor;
        int orL = __shfl_up(zor, 1);
        if (lane == 0) orL = 0;
        int orR = __shfl_down(zor, 1);
        if (lane == 63) orR = 0;
        const int pres0 = (zor | (zor >> 8) | (orL >> 8)) & 15;
        const int pres1 = (zor | (zor >> 8) | orR) & 15;

#pragma unroll
        for (int c = 0; c < 4; ++c) {
            const float2 ac = *(const float2*)(xb + (c << 21) + rbc);
            const float zpx = r0.ypx[c] * r1.ypx[c] * r2.ypx[c];
            const float zpy = r0.ypy[c] * r1.ypy[c] * r2.ypy[c];
            float zpL = __shfl_up(zpy, 1);
            if (lane == 0) zpL = 1.f;
            float zpR = __shfl_down(zpx, 1);
            if (lane == 63) zpR = 1.f;
            const float P0 = zpL * zpx * zpy;
            const float P1 = zpx * zpy * zpR;

            const float xv0 = ac.x, xv1 = ac.y;
            sx[c] += xv0 + xv1;
            const float m0 = (pres0 >> c & 1) ? 1.f : 2.f;
            const float m1 = (pres1 >> c & 1) ? 1.f : 2.f;
            fp[c] += (cc0 != c) ? xv0 * m0 : 0.f;
            fp[c] += (cc1 != c) ? xv1 * m1 : 0.f;
            fnv[c] += (cc0 == c) ? (1.f - xv0) * (1.f + P0) : 0.f;
            fnv[c] += (cc1 == c) ? (1.f - xv1) * (1.f + P1) : 0.f;
            sy[c] += (cc0 == c) ? 1.f : 0.f;
            sy[c] += (cc1 == c) ? 1.f : 0.f;
        }

        r0 = r1;
        r1 = r2;
    }

    // ---- block reduction of 16 scalars, then global atomics ----
    float r[16];
#pragma unroll
    for (int c = 0; c < 4; ++c) {
        r[c] = fp[c];
        r[4 + c] = fnv[c];
        r[8 + c] = sx[c];
        r[12 + c] = sy[c];
    }
    __shared__ float s[16];
#pragma unroll
    for (int i = 0; i < 16; ++i) {
        float vv = r[i];
#pragma unroll
        for (int off = 32; off >= 1; off >>= 1) vv += __shfl_down(vv, off);
        r[i] = vv;
    }
    if (threadIdx.x < 16) s[threadIdx.x] = 0.f;
    __syncthreads();
    if ((threadIdx.x & 63) == 0) {
#pragma unroll
        for (int i = 0; i < 16; ++i) atomicAdd(&s[i], r[i]);
    }
    __syncthreads();
    if (threadIdx.x < 16) atomicAdd(&acc[b * 16 + threadIdx.x], s[threadIdx.x]);
}

__global__ void lah_finalize(const float* __restrict__ acc, float* __restrict__ out) {
    float loss = 0.f;
#pragma unroll
    for (int b = 0; b < 2; ++b) {
#pragma unroll
        for (int c = 1; c < 4; ++c) {
            const float fp = acc[b * 16 + 0 + c];
            const float fn = acc[b * 16 + 4 + c];
            const float sxv = acc[b * 16 + 8 + c];
            const float syv = acc[b * 16 + 12 + c];
            loss += fmaxf(fp / (sxv + EPSV), fn / (syv + EPSV));
        }
    }
    out[0] = loss / 6.f;
}

extern "C" void kernel_launch(void* const* d_in, const int* in_sizes, int n_in,
                              void* d_out, int out_size, void* d_ws, size_t ws_size,
                              hipStream_t stream) {
    const float* x = (const float*)d_in[0];
    const int* y32 = (const int*)d_in[1];
    float* out = (float*)d_out;
    float* acc = (float*)d_ws;  // 32 floats

    hipMemsetAsync(d_ws, 0, 32 * sizeof(float), stream);
    lah_stencil<<<NBLK, 256, 0, stream>>>(x, y32, acc);
    lah_finalize<<<1, 1, 0, stream>>>(acc, out);
}